// Round 1
// baseline (482.108 us; speedup 1.0000x reference)
//
#include <hip/hip_runtime.h>
#include <math.h>

#define N_NODES 50000
#define N_EDGES 800000
#define FEAT 128
#define EPS_W 1e-12f

// ---------- helpers ----------
__device__ __forceinline__ float selu_f(float x) {
  const float scale = 1.0507009873554805f;
  const float alpha = 1.6732632423543772f;
  return x > 0.f ? scale * x : scale * alpha * expm1f(x);
}

// ---------- 1. degree accumulation (weighted + counts) ----------
__global__ __launch_bounds__(256) void degree_kernel(
    const int* __restrict__ src, const int* __restrict__ dst,
    const float* __restrict__ ew,
    float* __restrict__ wdeg_out, float* __restrict__ wdeg_in,
    int* __restrict__ cnt_out, int* __restrict__ cnt_in) {
  int e = blockIdx.x * 256 + threadIdx.x;
  if (e >= N_EDGES) return;
  int s = src[e], d = dst[e];
  float w = ew[e];
  atomicAdd(&wdeg_out[s], w);
  atomicAdd(&wdeg_in[d], w);
  atomicAdd(&cnt_out[s], 1);
  atomicAdd(&cnt_in[d], 1);
}

// ---------- 2. exclusive scan of cnt_in -> rowptr (3 small kernels) ----------
// block b covers elements [b*1024, b*1024+1024)
__global__ __launch_bounds__(256) void scan_partial(
    const int* __restrict__ cnt, int* __restrict__ partials, int n) {
  __shared__ int sdata[256];
  int base = blockIdx.x * 1024;
  int sum = 0;
  for (int j = 0; j < 4; ++j) {
    int i = base + j * 256 + threadIdx.x;
    sum += (i < n) ? cnt[i] : 0;
  }
  sdata[threadIdx.x] = sum;
  __syncthreads();
  for (int s = 128; s > 0; s >>= 1) {
    if (threadIdx.x < (unsigned)s) sdata[threadIdx.x] += sdata[threadIdx.x + s];
    __syncthreads();
  }
  if (threadIdx.x == 0) partials[blockIdx.x] = sdata[0];
}

__global__ void scan_small(int* __restrict__ partials, int nb) {
  int lane = threadIdx.x;  // launched with 64 threads, nb <= 64
  int v = (lane < nb) ? partials[lane] : 0;
  int incl = v;
#pragma unroll
  for (int off = 1; off < 64; off <<= 1) {
    int tv = __shfl_up(incl, off);
    if (lane >= off) incl += tv;
  }
  if (lane < nb) partials[lane] = incl - v;  // exclusive
}

__global__ __launch_bounds__(256) void scan_write(
    const int* __restrict__ cnt, const int* __restrict__ partials,
    int* __restrict__ rowptr, int* __restrict__ nextp, int n) {
  __shared__ int sh[256];
  int t = threadIdx.x;
  int base = blockIdx.x * 1024;
  int c[4], local[4], s = 0;
#pragma unroll
  for (int j = 0; j < 4; ++j) {
    int i = base + t * 4 + j;
    c[j] = (i < n) ? cnt[i] : 0;
    s += c[j];
    local[j] = s;  // inclusive within thread
  }
  sh[t] = s;
  __syncthreads();
  for (int off = 1; off < 256; off <<= 1) {
    int v = (t >= off) ? sh[t - off] : 0;
    __syncthreads();
    sh[t] += v;
    __syncthreads();
  }
  int thread_excl = sh[t] - s;
  int pbase = partials[blockIdx.x];
#pragma unroll
  for (int j = 0; j < 4; ++j) {
    int i = base + t * 4 + j;
    if (i < n) {
      int excl = pbase + thread_excl + local[j] - c[j];
      rowptr[i] = excl;
      nextp[i] = excl;
      if (i == n - 1) rowptr[n] = excl + c[j];
    }
  }
}

// ---------- 3. compute fused edge coefficient, scatter into CSR slots ----------
__global__ __launch_bounds__(256) void fill_kernel(
    const int* __restrict__ src, const int* __restrict__ dst,
    const float* __restrict__ ew,
    const float* __restrict__ wdeg_out, const float* __restrict__ wdeg_in,
    const int* __restrict__ cnt_out, const int* __restrict__ cnt_in,
    int* __restrict__ nextp, int* __restrict__ colsrc, float* __restrict__ ccsr) {
  int e = blockIdx.x * 256 + threadIdx.x;
  if (e >= N_EDGES) return;
  int s = src[e], d = dst[e];
  float w = ew[e];
  // EdgeWeightNorm('both') fused with GraphConv's symmetric count-degree norm.
  float c = w
      * (1.0f / sqrtf(fmaxf(wdeg_out[s], EPS_W)))
      * (1.0f / sqrtf(fmaxf(wdeg_in[d], EPS_W)))
      * (1.0f / sqrtf(fmaxf((float)cnt_out[s], 1.0f)))
      * (1.0f / sqrtf(fmaxf((float)cnt_in[d], 1.0f)));
  int pos = atomicAdd(&nextp[d], 1);
  colsrc[pos] = s;
  ccsr[pos] = c;
}

// ---------- 4. gather SpMM: one wave per dst row, float2 per lane ----------
__global__ __launch_bounds__(256) void spmm_csr(
    const int* __restrict__ rowptr, const int* __restrict__ colsrc,
    const float* __restrict__ coef, const float* __restrict__ x,
    float* __restrict__ out, int n) {
  int row = blockIdx.x * 4 + (threadIdx.x >> 6);
  if (row >= n) return;
  int lane = threadIdx.x & 63;
  int beg = rowptr[row], end = rowptr[row + 1];
  const float2* x2 = (const float2*)x;
  float2 acc = make_float2(0.f, 0.f);
  int e = beg;
  for (; e + 1 < end; e += 2) {
    int s0 = colsrc[e], s1 = colsrc[e + 1];
    float c0 = coef[e], c1 = coef[e + 1];
    float2 v0 = x2[s0 * 64 + lane];
    float2 v1 = x2[s1 * 64 + lane];
    acc.x += c0 * v0.x; acc.y += c0 * v0.y;
    acc.x += c1 * v1.x; acc.y += c1 * v1.y;
  }
  if (e < end) {
    int s0 = colsrc[e];
    float c0 = coef[e];
    float2 v0 = x2[s0 * 64 + lane];
    acc.x += c0 * v0.x; acc.y += c0 * v0.y;
  }
  ((float2*)out)[row * 64 + lane] = acc;
}

// ---------- 5. fp32 GEMM [n x 128] @ [128 x 128] + bias + selu ----------
// block = 256 threads handles 16 rows; thread = (col = t&63 covering col & col+64,
// rg = t>>6 covering rows rg*4 .. rg*4+3). A rows staged in LDS (broadcast reads).
__global__ __launch_bounds__(256) void gemm_bias_selu(
    const float* __restrict__ A, const float* __restrict__ W,
    const float* __restrict__ bias, float* __restrict__ out, int n) {
  __shared__ float aL[16 * 128];
  int row0 = blockIdx.x * 16;
  for (int i = threadIdx.x; i < 16 * 128; i += 256) {
    int r = row0 + (i >> 7);
    aL[i] = (r < n) ? A[row0 * 128 + i] : 0.f;
  }
  __syncthreads();
  int col = threadIdx.x & 63;
  int rg = threadIdx.x >> 6;  // 0..3
  float acc[4][2] = {};
#pragma unroll 4
  for (int k = 0; k < 128; ++k) {
    float w0 = W[k * 128 + col];
    float w1 = W[k * 128 + col + 64];
#pragma unroll
    for (int r = 0; r < 4; ++r) {
      float a = aL[(rg * 4 + r) * 128 + k];
      acc[r][0] += a * w0;
      acc[r][1] += a * w1;
    }
  }
  float b0 = bias[col], b1 = bias[col + 64];
#pragma unroll
  for (int r = 0; r < 4; ++r) {
    int row = row0 + rg * 4 + r;
    if (row < n) {
      out[row * 128 + col]      = selu_f(acc[r][0] + b0);
      out[row * 128 + col + 64] = selu_f(acc[r][1] + b1);
    }
  }
}

extern "C" void kernel_launch(void* const* d_in, const int* in_sizes, int n_in,
                              void* d_out, int out_size, void* d_ws, size_t ws_size,
                              hipStream_t stream) {
  const float* x   = (const float*)d_in[0];
  const int*   src = (const int*)d_in[1];
  const int*   dst = (const int*)d_in[2];
  const float* ew  = (const float*)d_in[3];
  const float* W1  = (const float*)d_in[4];
  const float* b1  = (const float*)d_in[5];
  const float* W2  = (const float*)d_in[6];
  const float* b2  = (const float*)d_in[7];
  float* out = (float*)d_out;

  // workspace layout (element offsets, all 16B-aligned where vector loads occur)
  float* wsf = (float*)d_ws;
  int*   wsi = (int*)d_ws;
  float* wdeg_out = wsf + 0;          // N floats
  float* wdeg_in  = wsf + 50000;      // N floats
  int*   cnt_out  = wsi + 100000;     // N ints
  int*   cnt_in   = wsi + 150000;     // N ints
  int*   rowptr   = wsi + 200000;     // N+1 ints
  int*   nextp    = wsi + 250004;     // N ints
  int*   partials = wsi + 300004;     // 64 ints
  int*   colsrc   = wsi + 300068;     // E ints
  float* ccsr     = wsf + 1100068;    // E floats
  float* bufA     = wsf + 1900068;    // N*128 floats (byte off mult of 16)
  float* bufB     = bufA + N_NODES * FEAT;  // N*128 floats

  // zero the 4 degree arrays (wdeg_out, wdeg_in, cnt_out, cnt_in)
  hipMemsetAsync(d_ws, 0, (size_t)(4 * N_NODES) * sizeof(float), stream);

  const int EB = (N_EDGES + 255) / 256;        // 3125
  const int SB = (N_NODES + 1023) / 1024;      // 49

  degree_kernel<<<EB, 256, 0, stream>>>(src, dst, ew, wdeg_out, wdeg_in, cnt_out, cnt_in);
  scan_partial<<<SB, 256, 0, stream>>>(cnt_in, partials, N_NODES);
  scan_small<<<1, 64, 0, stream>>>(partials, SB);
  scan_write<<<SB, 256, 0, stream>>>(cnt_in, partials, rowptr, nextp, N_NODES);
  fill_kernel<<<EB, 256, 0, stream>>>(src, dst, ew, wdeg_out, wdeg_in, cnt_out, cnt_in,
                                      nextp, colsrc, ccsr);

  const int AB = (N_NODES + 3) / 4;            // 12500 (4 rows / block)
  const int GB = (N_NODES + 15) / 16;          // 3125  (16 rows / block)

  // layer 1: agg = A_hat * x ; h = selu(agg @ W1 + b1)
  spmm_csr<<<AB, 256, 0, stream>>>(rowptr, colsrc, ccsr, x, bufA, N_NODES);
  gemm_bias_selu<<<GB, 256, 0, stream>>>(bufA, W1, b1, bufB, N_NODES);
  // layer 2: agg2 = A_hat * h ; out = selu(agg2 @ W2 + b2)
  spmm_csr<<<AB, 256, 0, stream>>>(rowptr, colsrc, ccsr, bufB, bufA, N_NODES);
  gemm_bias_selu<<<GB, 256, 0, stream>>>(bufA, W2, b2, out, N_NODES);
}

// Round 2
// 430.973 us; speedup vs baseline: 1.1187x; 1.1187x over previous
//
#include <hip/hip_runtime.h>
#include <math.h>

#define N_NODES 50000
#define N_EDGES 800000
#define FEAT 128
#define EPS_W 1e-12f

// Q24 fixed-point packing: low 40 bits = sum of w*2^24, high 24 bits = count.
#define WSCALE 16777216.0f
#define MASK40 ((1ull << 40) - 1)

typedef unsigned long long u64;

// ---------- helpers ----------
__device__ __forceinline__ float selu_f(float x) {
  const float scale = 1.0507009873554805f;
  const float alpha = 1.6732632423543772f;
  return x > 0.f ? scale * x : scale * alpha * expm1f(x);
}

// ---------- 1. degree accumulation: ONE 64-bit atomic per (edge,endpoint) ----------
__global__ __launch_bounds__(256) void degree_kernel(
    const int* __restrict__ src, const int* __restrict__ dst,
    const float* __restrict__ ew,
    u64* __restrict__ acc_out, u64* __restrict__ acc_in) {
  int e = blockIdx.x * 256 + threadIdx.x;
  if (e >= N_EDGES) return;
  int s = src[e], d = dst[e];
  float w = ew[e];
  u64 p = (1ull << 40) | (u64)llrintf(w * WSCALE);
  atomicAdd(&acc_out[s], p);
  atomicAdd(&acc_in[d], p);
}

// ---------- 1b. per-node fused inverse norms ----------
__global__ __launch_bounds__(256) void node_inv_kernel(
    const u64* __restrict__ acc_out, const u64* __restrict__ acc_in,
    float* __restrict__ inv_out, float* __restrict__ inv_in) {
  int v = blockIdx.x * 256 + threadIdx.x;
  if (v >= N_NODES) return;
  u64 po = acc_out[v], pi = acc_in[v];
  float wo = (float)(po & MASK40) * (1.0f / WSCALE);
  float wi = (float)(pi & MASK40) * (1.0f / WSCALE);
  float co = (float)(po >> 40);
  float ci = (float)(pi >> 40);
  inv_out[v] = (1.0f / sqrtf(fmaxf(wo, EPS_W))) * (1.0f / sqrtf(fmaxf(co, 1.0f)));
  inv_in[v]  = (1.0f / sqrtf(fmaxf(wi, EPS_W))) * (1.0f / sqrtf(fmaxf(ci, 1.0f)));
}

// ---------- 2. exclusive scan of in-counts -> rowptr ----------
// block b covers elements [b*1024, b*1024+1024)
__global__ __launch_bounds__(256) void scan_partial(
    const u64* __restrict__ acc_in, int* __restrict__ partials, int n) {
  __shared__ int sdata[256];
  int base = blockIdx.x * 1024;
  int sum = 0;
  for (int j = 0; j < 4; ++j) {
    int i = base + j * 256 + threadIdx.x;
    sum += (i < n) ? (int)(acc_in[i] >> 40) : 0;
  }
  sdata[threadIdx.x] = sum;
  __syncthreads();
  for (int s = 128; s > 0; s >>= 1) {
    if (threadIdx.x < (unsigned)s) sdata[threadIdx.x] += sdata[threadIdx.x + s];
    __syncthreads();
  }
  if (threadIdx.x == 0) partials[blockIdx.x] = sdata[0];
}

__global__ void scan_small(int* __restrict__ partials, int nb) {
  int lane = threadIdx.x;  // launched with 64 threads, nb <= 64
  int v = (lane < nb) ? partials[lane] : 0;
  int incl = v;
#pragma unroll
  for (int off = 1; off < 64; off <<= 1) {
    int tv = __shfl_up(incl, off);
    if (lane >= off) incl += tv;
  }
  if (lane < nb) partials[lane] = incl - v;  // exclusive
}

__global__ __launch_bounds__(256) void scan_write(
    const u64* __restrict__ acc_in, const int* __restrict__ partials,
    int* __restrict__ rowptr, int* __restrict__ nextp, int n) {
  __shared__ int sh[256];
  int t = threadIdx.x;
  int base = blockIdx.x * 1024;
  int c[4], local[4], s = 0;
#pragma unroll
  for (int j = 0; j < 4; ++j) {
    int i = base + t * 4 + j;
    c[j] = (i < n) ? (int)(acc_in[i] >> 40) : 0;
    s += c[j];
    local[j] = s;  // inclusive within thread
  }
  sh[t] = s;
  __syncthreads();
  for (int off = 1; off < 256; off <<= 1) {
    int v = (t >= off) ? sh[t - off] : 0;
    __syncthreads();
    sh[t] += v;
    __syncthreads();
  }
  int thread_excl = sh[t] - s;
  int pbase = partials[blockIdx.x];
#pragma unroll
  for (int j = 0; j < 4; ++j) {
    int i = base + t * 4 + j;
    if (i < n) {
      int excl = pbase + thread_excl + local[j] - c[j];
      rowptr[i] = excl;
      nextp[i] = excl;
      if (i == n - 1) rowptr[n] = excl + c[j];
    }
  }
}

// ---------- 3. fused edge coefficient, scatter into CSR slots ----------
__global__ __launch_bounds__(256) void fill_kernel(
    const int* __restrict__ src, const int* __restrict__ dst,
    const float* __restrict__ ew,
    const float* __restrict__ inv_out, const float* __restrict__ inv_in,
    int* __restrict__ nextp, int* __restrict__ colsrc, float* __restrict__ ccsr) {
  int e = blockIdx.x * 256 + threadIdx.x;
  if (e >= N_EDGES) return;
  int s = src[e], d = dst[e];
  float c = ew[e] * inv_out[s] * inv_in[d];
  int pos = atomicAdd(&nextp[d], 1);
  colsrc[pos] = s;
  ccsr[pos] = c;
}

// ---------- 4. gather SpMM: one wave per dst row, float2 per lane ----------
__global__ __launch_bounds__(256) void spmm_csr(
    const int* __restrict__ rowptr, const int* __restrict__ colsrc,
    const float* __restrict__ coef, const float* __restrict__ x,
    float* __restrict__ out, int n) {
  int row = blockIdx.x * 4 + (threadIdx.x >> 6);
  if (row >= n) return;
  int lane = threadIdx.x & 63;
  int beg = rowptr[row], end = rowptr[row + 1];
  const float2* x2 = (const float2*)x;
  float2 acc = make_float2(0.f, 0.f);
  int e = beg;
  for (; e + 1 < end; e += 2) {
    int s0 = colsrc[e], s1 = colsrc[e + 1];
    float c0 = coef[e], c1 = coef[e + 1];
    float2 v0 = x2[s0 * 64 + lane];
    float2 v1 = x2[s1 * 64 + lane];
    acc.x += c0 * v0.x; acc.y += c0 * v0.y;
    acc.x += c1 * v1.x; acc.y += c1 * v1.y;
  }
  if (e < end) {
    int s0 = colsrc[e];
    float c0 = coef[e];
    float2 v0 = x2[s0 * 64 + lane];
    acc.x += c0 * v0.x; acc.y += c0 * v0.y;
  }
  ((float2*)out)[row * 64 + lane] = acc;
}

// ---------- 5. fp32 GEMM [n x 128] @ [128 x 128] + bias + selu ----------
__global__ __launch_bounds__(256) void gemm_bias_selu(
    const float* __restrict__ A, const float* __restrict__ W,
    const float* __restrict__ bias, float* __restrict__ out, int n) {
  __shared__ float aL[16 * 128];
  int row0 = blockIdx.x * 16;
  for (int i = threadIdx.x; i < 16 * 128; i += 256) {
    int r = row0 + (i >> 7);
    aL[i] = (r < n) ? A[row0 * 128 + i] : 0.f;
  }
  __syncthreads();
  int col = threadIdx.x & 63;
  int rg = threadIdx.x >> 6;  // 0..3
  float acc[4][2] = {};
#pragma unroll 4
  for (int k = 0; k < 128; ++k) {
    float w0 = W[k * 128 + col];
    float w1 = W[k * 128 + col + 64];
#pragma unroll
    for (int r = 0; r < 4; ++r) {
      float a = aL[(rg * 4 + r) * 128 + k];
      acc[r][0] += a * w0;
      acc[r][1] += a * w1;
    }
  }
  float b0 = bias[col], b1 = bias[col + 64];
#pragma unroll
  for (int r = 0; r < 4; ++r) {
    int row = row0 + rg * 4 + r;
    if (row < n) {
      out[row * 128 + col]      = selu_f(acc[r][0] + b0);
      out[row * 128 + col + 64] = selu_f(acc[r][1] + b1);
    }
  }
}

extern "C" void kernel_launch(void* const* d_in, const int* in_sizes, int n_in,
                              void* d_out, int out_size, void* d_ws, size_t ws_size,
                              hipStream_t stream) {
  const float* x   = (const float*)d_in[0];
  const int*   src = (const int*)d_in[1];
  const int*   dst = (const int*)d_in[2];
  const float* ew  = (const float*)d_in[3];
  const float* W1  = (const float*)d_in[4];
  const float* b1  = (const float*)d_in[5];
  const float* W2  = (const float*)d_in[6];
  const float* b2  = (const float*)d_in[7];
  float* out = (float*)d_out;

  // workspace layout (byte offsets; 8B-aligned for u64, 16B-aligned for float2 bufs)
  char* ws = (char*)d_ws;
  u64*   acc_out  = (u64*)(ws + 0);           //  400,000 B
  u64*   acc_in   = (u64*)(ws + 400000);      //  400,000 B
  float* inv_out  = (float*)(ws + 800000);    //  200,000 B
  float* inv_in   = (float*)(ws + 1000000);   //  200,000 B
  int*   rowptr   = (int*)(ws + 1200000);     //  200,004 B
  int*   nextp    = (int*)(ws + 1400004);     //  200,000 B
  int*   partials = (int*)(ws + 1600004);     //      256 B
  int*   colsrc   = (int*)(ws + 1600260);     // 3,200,000 B
  float* ccsr     = (float*)(ws + 4800260);   // 3,200,000 B
  float* bufA     = (float*)(ws + 8000272);   // 25,600,000 B (16B aligned)
  float* bufB     = bufA + (size_t)N_NODES * FEAT;

  // zero the two packed degree accumulators
  hipMemsetAsync(d_ws, 0, (size_t)(2 * N_NODES) * sizeof(u64), stream);

  const int EB = (N_EDGES + 255) / 256;        // 3125
  const int NB = (N_NODES + 255) / 256;        // 196
  const int SB = (N_NODES + 1023) / 1024;      // 49

  degree_kernel<<<EB, 256, 0, stream>>>(src, dst, ew, acc_out, acc_in);
  node_inv_kernel<<<NB, 256, 0, stream>>>(acc_out, acc_in, inv_out, inv_in);
  scan_partial<<<SB, 256, 0, stream>>>(acc_in, partials, N_NODES);
  scan_small<<<1, 64, 0, stream>>>(partials, SB);
  scan_write<<<SB, 256, 0, stream>>>(acc_in, partials, rowptr, nextp, N_NODES);
  fill_kernel<<<EB, 256, 0, stream>>>(src, dst, ew, inv_out, inv_in,
                                      nextp, colsrc, ccsr);

  const int AB = (N_NODES + 3) / 4;            // 12500 (4 rows / block)
  const int GB = (N_NODES + 15) / 16;          // 3125  (16 rows / block)

  // layer 1: agg = A_hat * x ; h = selu(agg @ W1 + b1)
  spmm_csr<<<AB, 256, 0, stream>>>(rowptr, colsrc, ccsr, x, bufA, N_NODES);
  gemm_bias_selu<<<GB, 256, 0, stream>>>(bufA, W1, b1, bufB, N_NODES);
  // layer 2: agg2 = A_hat * h ; out = selu(agg2 @ W2 + b2)
  spmm_csr<<<AB, 256, 0, stream>>>(rowptr, colsrc, ccsr, bufB, bufA, N_NODES);
  gemm_bias_selu<<<GB, 256, 0, stream>>>(bufA, W2, b2, out, N_NODES);
}

// Round 3
// 383.298 us; speedup vs baseline: 1.2578x; 1.1244x over previous
//
#include <hip/hip_runtime.h>
#include <math.h>

#define N_NODES 50000
#define N_EDGES 800000
#define FEAT 128
#define EPS_W 1e-12f

// Q24 fixed-point packing: low 40 bits = sum of w*2^24, high 24 bits = count.
#define WSCALE 16777216.0f
#define MASK40 ((1ull << 40) - 1)

#define EDGE_BLOCKS 3125   // 800000 / 256
#define GEMM_BLOCKS 3125   // 50000 / 16

typedef unsigned long long u64;

// ---------- helpers ----------
__device__ __forceinline__ float selu_f(float x) {
  const float scale = 1.0507009873554805f;
  const float alpha = 1.6732632423543772f;
  return x > 0.f ? scale * x : scale * alpha * expm1f(x);
}

// ---------- GEMM body: 16 rows of A (n x 128) @ W (128 x 128) -> out, no epilogue
__device__ __forceinline__ void gemm16_body(
    const float* __restrict__ A, const float* __restrict__ W,
    float* __restrict__ out, int row0, int n, float* aL /*16*128 LDS*/) {
  for (int i = threadIdx.x; i < 16 * 128; i += 256) {
    int r = row0 + (i >> 7);
    aL[i] = (r < n) ? A[row0 * 128 + i] : 0.f;
  }
  __syncthreads();
  int col = threadIdx.x & 63;
  int rg = threadIdx.x >> 6;  // 0..3
  float acc[4][2] = {};
#pragma unroll 4
  for (int k = 0; k < 128; ++k) {
    float w0 = W[k * 128 + col];
    float w1 = W[k * 128 + col + 64];
#pragma unroll
    for (int r = 0; r < 4; ++r) {
      float a = aL[(rg * 4 + r) * 128 + k];
      acc[r][0] += a * w0;
      acc[r][1] += a * w1;
    }
  }
#pragma unroll
  for (int r = 0; r < 4; ++r) {
    int row = row0 + rg * 4 + r;
    if (row < n) {
      out[row * 128 + col]      = acc[r][0];
      out[row * 128 + col + 64] = acc[r][1];
    }
  }
}

// ---------- 1. FUSED: degree atomics (odd blocks) || x@W1 GEMM (even blocks) ----
// Degree is atomic-latency bound (VALU 0.6%, HBM 9.6%) -> the GEMM's VALU work
// co-schedules under it for free (m114 co-residency).
__global__ __launch_bounds__(256) void fused_deg_gemm(
    const int* __restrict__ src, const int* __restrict__ dst,
    const float* __restrict__ ew,
    u64* __restrict__ acc_out, u64* __restrict__ acc_in,
    const float* __restrict__ x, const float* __restrict__ W1,
    float* __restrict__ bufG) {
  __shared__ float aL[16 * 128];
  if (blockIdx.x & 1) {
    // degree half
    int e = (blockIdx.x >> 1) * 256 + threadIdx.x;
    if (e >= N_EDGES) return;
    int s = src[e], d = dst[e];
    float w = ew[e];
    u64 p = (1ull << 40) | (u64)llrintf(w * WSCALE);
    atomicAdd(&acc_out[s], p);
    atomicAdd(&acc_in[d], p);
  } else {
    // GEMM half: bufG = x @ W1 (bias+selu deferred to spmm epilogue)
    int row0 = (blockIdx.x >> 1) * 16;
    gemm16_body(x, W1, bufG, row0, N_NODES, aL);
  }
}

// ---------- 2. per-node inverse norms + scan partials (fused) ----------
// block b covers nodes [b*1024, b*1024+1024)
__global__ __launch_bounds__(256) void node_inv_scan(
    const u64* __restrict__ acc_out, const u64* __restrict__ acc_in,
    float* __restrict__ inv_out, float* __restrict__ inv_in,
    int* __restrict__ partials, int n) {
  __shared__ int sdata[256];
  int base = blockIdx.x * 1024;
  int sum = 0;
  for (int j = 0; j < 4; ++j) {
    int i = base + j * 256 + threadIdx.x;
    if (i < n) {
      u64 po = acc_out[i], pi = acc_in[i];
      float wo = (float)(po & MASK40) * (1.0f / WSCALE);
      float wi = (float)(pi & MASK40) * (1.0f / WSCALE);
      float co = (float)(po >> 40);
      float ci = (float)(pi >> 40);
      inv_out[i] = (1.0f / sqrtf(fmaxf(wo, EPS_W))) * (1.0f / sqrtf(fmaxf(co, 1.0f)));
      inv_in[i]  = (1.0f / sqrtf(fmaxf(wi, EPS_W))) * (1.0f / sqrtf(fmaxf(ci, 1.0f)));
      sum += (int)(pi >> 40);
    }
  }
  sdata[threadIdx.x] = sum;
  __syncthreads();
  for (int s = 128; s > 0; s >>= 1) {
    if (threadIdx.x < (unsigned)s) sdata[threadIdx.x] += sdata[threadIdx.x + s];
    __syncthreads();
  }
  if (threadIdx.x == 0) partials[blockIdx.x] = sdata[0];
}

__global__ void scan_small(int* __restrict__ partials, int nb) {
  int lane = threadIdx.x;  // launched with 64 threads, nb <= 64
  int v = (lane < nb) ? partials[lane] : 0;
  int incl = v;
#pragma unroll
  for (int off = 1; off < 64; off <<= 1) {
    int tv = __shfl_up(incl, off);
    if (lane >= off) incl += tv;
  }
  if (lane < nb) partials[lane] = incl - v;  // exclusive
}

__global__ __launch_bounds__(256) void scan_write(
    const u64* __restrict__ acc_in, const int* __restrict__ partials,
    int* __restrict__ rowptr, int* __restrict__ nextp, int n) {
  __shared__ int sh[256];
  int t = threadIdx.x;
  int base = blockIdx.x * 1024;
  int c[4], local[4], s = 0;
#pragma unroll
  for (int j = 0; j < 4; ++j) {
    int i = base + t * 4 + j;
    c[j] = (i < n) ? (int)(acc_in[i] >> 40) : 0;
    s += c[j];
    local[j] = s;  // inclusive within thread
  }
  sh[t] = s;
  __syncthreads();
  for (int off = 1; off < 256; off <<= 1) {
    int v = (t >= off) ? sh[t - off] : 0;
    __syncthreads();
    sh[t] += v;
    __syncthreads();
  }
  int thread_excl = sh[t] - s;
  int pbase = partials[blockIdx.x];
#pragma unroll
  for (int j = 0; j < 4; ++j) {
    int i = base + t * 4 + j;
    if (i < n) {
      int excl = pbase + thread_excl + local[j] - c[j];
      rowptr[i] = excl;
      nextp[i] = excl;
      if (i == n - 1) rowptr[n] = excl + c[j];
    }
  }
}

// ---------- 3. fused edge coefficient, scatter packed (src,coef) into CSR ------
__global__ __launch_bounds__(256) void fill_kernel(
    const int* __restrict__ src, const int* __restrict__ dst,
    const float* __restrict__ ew,
    const float* __restrict__ inv_out, const float* __restrict__ inv_in,
    int* __restrict__ nextp, int2* __restrict__ edges) {
  int e = blockIdx.x * 256 + threadIdx.x;
  if (e >= N_EDGES) return;
  int s = src[e], d = dst[e];
  float c = ew[e] * inv_out[s] * inv_in[d];
  int pos = atomicAdd(&nextp[d], 1);
  int2 rec; rec.x = s; rec.y = __float_as_int(c);
  edges[pos] = rec;  // single 8B scattered store
}

// ---------- 4. gather SpMM + bias + selu: one wave per dst row, float2/lane ----
__global__ __launch_bounds__(256) void spmm_ep(
    const int* __restrict__ rowptr, const int2* __restrict__ edges,
    const float* __restrict__ x, const float* __restrict__ bias,
    float* __restrict__ out, int n) {
  int row = blockIdx.x * 4 + (threadIdx.x >> 6);
  if (row >= n) return;
  int lane = threadIdx.x & 63;
  int beg = rowptr[row], end = rowptr[row + 1];
  const float2* x2 = (const float2*)x;
  float2 a0 = make_float2(0.f, 0.f), a1 = make_float2(0.f, 0.f);
  int e = beg;
  for (; e + 3 < end; e += 4) {
    int2 e0 = edges[e], e1 = edges[e + 1], e2 = edges[e + 2], e3 = edges[e + 3];
    float2 v0 = x2[(size_t)e0.x * 64 + lane];
    float2 v1 = x2[(size_t)e1.x * 64 + lane];
    float2 v2 = x2[(size_t)e2.x * 64 + lane];
    float2 v3 = x2[(size_t)e3.x * 64 + lane];
    float c0 = __int_as_float(e0.y), c1 = __int_as_float(e1.y);
    float c2 = __int_as_float(e2.y), c3 = __int_as_float(e3.y);
    a0.x += c0 * v0.x; a0.y += c0 * v0.y;
    a1.x += c1 * v1.x; a1.y += c1 * v1.y;
    a0.x += c2 * v2.x; a0.y += c2 * v2.y;
    a1.x += c3 * v3.x; a1.y += c3 * v3.y;
  }
  for (; e < end; ++e) {
    int2 e0 = edges[e];
    float2 v0 = x2[(size_t)e0.x * 64 + lane];
    float c0 = __int_as_float(e0.y);
    a0.x += c0 * v0.x; a0.y += c0 * v0.y;
  }
  float2 b = ((const float2*)bias)[lane];
  float2 r;
  r.x = selu_f(a0.x + a1.x + b.x);
  r.y = selu_f(a0.y + a1.y + b.y);
  ((float2*)out)[(size_t)row * 64 + lane] = r;
}

// ---------- 5. plain GEMM [n x 128] @ [128 x 128] (no epilogue) ----------
__global__ __launch_bounds__(256) void gemm_plain(
    const float* __restrict__ A, const float* __restrict__ W,
    float* __restrict__ out, int n) {
  __shared__ float aL[16 * 128];
  gemm16_body(A, W, out, blockIdx.x * 16, n, aL);
}

extern "C" void kernel_launch(void* const* d_in, const int* in_sizes, int n_in,
                              void* d_out, int out_size, void* d_ws, size_t ws_size,
                              hipStream_t stream) {
  const float* x   = (const float*)d_in[0];
  const int*   src = (const int*)d_in[1];
  const int*   dst = (const int*)d_in[2];
  const float* ew  = (const float*)d_in[3];
  const float* W1  = (const float*)d_in[4];
  const float* b1  = (const float*)d_in[5];
  const float* W2  = (const float*)d_in[6];
  const float* b2  = (const float*)d_in[7];
  float* out = (float*)d_out;

  // workspace layout (byte offsets; 8B-aligned for u64/int2, 16B for row bufs)
  char* ws = (char*)d_ws;
  u64*   acc_out  = (u64*)(ws + 0);           //  400,000 B
  u64*   acc_in   = (u64*)(ws + 400000);      //  400,000 B
  float* inv_out  = (float*)(ws + 800000);    //  200,000 B
  float* inv_in   = (float*)(ws + 1000000);   //  200,000 B
  int*   rowptr   = (int*)(ws + 1200000);     //  200,004 B
  int*   nextp    = (int*)(ws + 1400004);     //  200,000 B
  int*   partials = (int*)(ws + 1600004);     //      256 B
  int2*  edges    = (int2*)(ws + 1600264);    // 6,400,000 B (packed src+coef)
  float* bufG     = (float*)(ws + 8000272);   // 25,600,000 B
  float* bufB     = bufG + (size_t)N_NODES * FEAT;  // 25,600,000 B

  // zero the two packed degree accumulators
  hipMemsetAsync(d_ws, 0, (size_t)(2 * N_NODES) * sizeof(u64), stream);

  const int NB1K = (N_NODES + 1023) / 1024;    // 49

  // 1. degree atomics || bufG = x @ W1 (graph-independent, overlapped)
  fused_deg_gemm<<<EDGE_BLOCKS + GEMM_BLOCKS, 256, 0, stream>>>(
      src, dst, ew, acc_out, acc_in, x, W1, bufG);
  // 2. norms + CSR rowptr
  node_inv_scan<<<NB1K, 256, 0, stream>>>(acc_out, acc_in, inv_out, inv_in,
                                          partials, N_NODES);
  scan_small<<<1, 64, 0, stream>>>(partials, NB1K);
  scan_write<<<NB1K, 256, 0, stream>>>(acc_in, partials, rowptr, nextp, N_NODES);
  // 3. CSR fill with fused coefficient
  fill_kernel<<<EDGE_BLOCKS, 256, 0, stream>>>(src, dst, ew, inv_out, inv_in,
                                               nextp, edges);

  const int AB = (N_NODES + 3) / 4;            // 12500 (4 rows / block)

  // layer 1: h = selu(A_hat·(x@W1) + b1)   [linear-map associativity]
  spmm_ep<<<AB, 256, 0, stream>>>(rowptr, edges, bufG, b1, bufB, N_NODES);
  // layer 2: out = selu(A_hat·(h@W2) + b2)
  gemm_plain<<<GEMM_BLOCKS, 256, 0, stream>>>(bufB, W2, bufG, N_NODES);
  spmm_ep<<<AB, 256, 0, stream>>>(rowptr, edges, bufG, b2, out, N_NODES);
}

// Round 4
// 380.718 us; speedup vs baseline: 1.2663x; 1.0068x over previous
//
#include <hip/hip_runtime.h>
#include <math.h>

#define N_NODES 50000
#define N_EDGES 800000
#define FEAT 128
#define EPS_W 1e-12f

// Q24 fixed-point packing: low 40 bits = sum of w*2^24, high 24 bits = count.
#define WSCALE 16777216.0f
#define MASK40 ((1ull << 40) - 1)

#define EDGE_BLOCKS 3125   // 800000 / 256
#define GEMM_BLOCKS 3125   // 50000 / 16

typedef unsigned long long u64;

// ---------- helpers ----------
__device__ __forceinline__ float selu_f(float x) {
  const float scale = 1.0507009873554805f;
  const float alpha = 1.6732632423543772f;
  return x > 0.f ? scale * x : scale * alpha * expm1f(x);
}

// ---------- GEMM body: 16 rows of A (n x 128) @ W (128 x 128) -> out ----------
__device__ __forceinline__ void gemm16_body(
    const float* __restrict__ A, const float* __restrict__ W,
    float* __restrict__ out, int row0, int n, float* aL /*16*128 LDS*/) {
  for (int i = threadIdx.x; i < 16 * 128; i += 256) {
    int r = row0 + (i >> 7);
    aL[i] = (r < n) ? A[row0 * 128 + i] : 0.f;
  }
  __syncthreads();
  int col = threadIdx.x & 63;
  int rg = threadIdx.x >> 6;  // 0..3
  float acc[4][2] = {};
#pragma unroll 4
  for (int k = 0; k < 128; ++k) {
    float w0 = W[k * 128 + col];
    float w1 = W[k * 128 + col + 64];
#pragma unroll
    for (int r = 0; r < 4; ++r) {
      float a = aL[(rg * 4 + r) * 128 + k];
      acc[r][0] += a * w0;
      acc[r][1] += a * w1;
    }
  }
#pragma unroll
  for (int r = 0; r < 4; ++r) {
    int row = row0 + rg * 4 + r;
    if (row < n) {
      out[row * 128 + col]      = acc[r][0];
      out[row * 128 + col + 64] = acc[r][1];
    }
  }
}

// ---------- 1. FUSED: degree atomics (odd blocks) || x@W1 GEMM (even blocks) ----
// Degree is fabric-atomic-rate bound (~22 atomics/ns, VALU ~0.6%) -> the GEMM's
// VALU work co-schedules under it nearly for free (m114 co-residency).
__global__ __launch_bounds__(256) void fused_deg_gemm(
    const int* __restrict__ src, const int* __restrict__ dst,
    const float* __restrict__ ew,
    u64* __restrict__ acc_out, u64* __restrict__ acc_in,
    const float* __restrict__ x, const float* __restrict__ W1,
    float* __restrict__ bufG) {
  __shared__ float aL[16 * 128];
  if (blockIdx.x & 1) {
    // degree half: ONE packed 64-bit atomic per (edge,endpoint)
    int e = (blockIdx.x >> 1) * 256 + threadIdx.x;
    if (e >= N_EDGES) return;
    int s = src[e], d = dst[e];
    float w = ew[e];
    u64 p = (1ull << 40) | (u64)llrintf(w * WSCALE);
    atomicAdd(&acc_out[s], p);
    atomicAdd(&acc_in[d], p);
  } else {
    // GEMM half: bufG = x @ W1 (bias+selu deferred to spmm epilogue)
    int row0 = (blockIdx.x >> 1) * 16;
    gemm16_body(x, W1, bufG, row0, N_NODES, aL);
  }
}

// ---------- 2. per-node inverse norms + scan partials (fused) ----------
__global__ __launch_bounds__(256) void node_inv_scan(
    const u64* __restrict__ acc_out, const u64* __restrict__ acc_in,
    float* __restrict__ inv_out, float* __restrict__ inv_in,
    int* __restrict__ partials, int n) {
  __shared__ int sdata[256];
  int base = blockIdx.x * 1024;
  int sum = 0;
  for (int j = 0; j < 4; ++j) {
    int i = base + j * 256 + threadIdx.x;
    if (i < n) {
      u64 po = acc_out[i], pi = acc_in[i];
      float wo = (float)(po & MASK40) * (1.0f / WSCALE);
      float wi = (float)(pi & MASK40) * (1.0f / WSCALE);
      float co = (float)(po >> 40);
      float ci = (float)(pi >> 40);
      inv_out[i] = (1.0f / sqrtf(fmaxf(wo, EPS_W))) * (1.0f / sqrtf(fmaxf(co, 1.0f)));
      inv_in[i]  = (1.0f / sqrtf(fmaxf(wi, EPS_W))) * (1.0f / sqrtf(fmaxf(ci, 1.0f)));
      sum += (int)(pi >> 40);
    }
  }
  sdata[threadIdx.x] = sum;
  __syncthreads();
  for (int s = 128; s > 0; s >>= 1) {
    if (threadIdx.x < (unsigned)s) sdata[threadIdx.x] += sdata[threadIdx.x + s];
    __syncthreads();
  }
  if (threadIdx.x == 0) partials[blockIdx.x] = sdata[0];
}

__global__ void scan_small(int* __restrict__ partials, int nb) {
  int lane = threadIdx.x;  // launched with 64 threads, nb <= 64
  int v = (lane < nb) ? partials[lane] : 0;
  int incl = v;
#pragma unroll
  for (int off = 1; off < 64; off <<= 1) {
    int tv = __shfl_up(incl, off);
    if (lane >= off) incl += tv;
  }
  if (lane < nb) partials[lane] = incl - v;  // exclusive
}

__global__ __launch_bounds__(256) void scan_write(
    const u64* __restrict__ acc_in, const int* __restrict__ partials,
    int* __restrict__ rowptr, int* __restrict__ nextp, int n) {
  __shared__ int sh[256];
  int t = threadIdx.x;
  int base = blockIdx.x * 1024;
  int c[4], local[4], s = 0;
#pragma unroll
  for (int j = 0; j < 4; ++j) {
    int i = base + t * 4 + j;
    c[j] = (i < n) ? (int)(acc_in[i] >> 40) : 0;
    s += c[j];
    local[j] = s;  // inclusive within thread
  }
  sh[t] = s;
  __syncthreads();
  for (int off = 1; off < 256; off <<= 1) {
    int v = (t >= off) ? sh[t - off] : 0;
    __syncthreads();
    sh[t] += v;
    __syncthreads();
  }
  int thread_excl = sh[t] - s;
  int pbase = partials[blockIdx.x];
#pragma unroll
  for (int j = 0; j < 4; ++j) {
    int i = base + t * 4 + j;
    if (i < n) {
      int excl = pbase + thread_excl + local[j] - c[j];
      rowptr[i] = excl;
      nextp[i] = excl;
      if (i == n - 1) rowptr[n] = excl + c[j];
    }
  }
}

// ---------- 3. fused edge coefficient, scatter packed (src,coef) into CSR ------
__global__ __launch_bounds__(256) void fill_kernel(
    const int* __restrict__ src, const int* __restrict__ dst,
    const float* __restrict__ ew,
    const float* __restrict__ inv_out, const float* __restrict__ inv_in,
    int* __restrict__ nextp, int2* __restrict__ edges) {
  int e = blockIdx.x * 256 + threadIdx.x;
  if (e >= N_EDGES) return;
  int s = src[e], d = dst[e];
  float c = ew[e] * inv_out[s] * inv_in[d];
  int pos = atomicAdd(&nextp[d], 1);
  int2 rec; rec.x = s; rec.y = __float_as_int(c);
  edges[pos] = rec;  // single 8B scattered store
}

// ---------- gather one dst row: unroll 8, 16 outstanding loads/wave ----------
__device__ __forceinline__ float2 gather_row(
    const int* __restrict__ rowptr, const int2* __restrict__ edges,
    const float2* __restrict__ x2, int row, int lane) {
  int beg = rowptr[row], end = rowptr[row + 1];
  float2 a0 = make_float2(0.f, 0.f), a1 = a0, a2 = a0, a3 = a0;
  int e = beg;
  for (; e + 7 < end; e += 8) {
    int2 p0 = edges[e + 0], p1 = edges[e + 1], p2 = edges[e + 2], p3 = edges[e + 3];
    int2 p4 = edges[e + 4], p5 = edges[e + 5], p6 = edges[e + 6], p7 = edges[e + 7];
    float2 v0 = x2[(size_t)p0.x * 64 + lane];
    float2 v1 = x2[(size_t)p1.x * 64 + lane];
    float2 v2 = x2[(size_t)p2.x * 64 + lane];
    float2 v3 = x2[(size_t)p3.x * 64 + lane];
    float2 v4 = x2[(size_t)p4.x * 64 + lane];
    float2 v5 = x2[(size_t)p5.x * 64 + lane];
    float2 v6 = x2[(size_t)p6.x * 64 + lane];
    float2 v7 = x2[(size_t)p7.x * 64 + lane];
    float c0 = __int_as_float(p0.y), c1 = __int_as_float(p1.y);
    float c2 = __int_as_float(p2.y), c3 = __int_as_float(p3.y);
    float c4 = __int_as_float(p4.y), c5 = __int_as_float(p5.y);
    float c6 = __int_as_float(p6.y), c7 = __int_as_float(p7.y);
    a0.x += c0 * v0.x; a0.y += c0 * v0.y;
    a1.x += c1 * v1.x; a1.y += c1 * v1.y;
    a2.x += c2 * v2.x; a2.y += c2 * v2.y;
    a3.x += c3 * v3.x; a3.y += c3 * v3.y;
    a0.x += c4 * v4.x; a0.y += c4 * v4.y;
    a1.x += c5 * v5.x; a1.y += c5 * v5.y;
    a2.x += c6 * v6.x; a2.y += c6 * v6.y;
    a3.x += c7 * v7.x; a3.y += c7 * v7.y;
  }
  for (; e + 1 < end; e += 2) {
    int2 p0 = edges[e], p1 = edges[e + 1];
    float2 v0 = x2[(size_t)p0.x * 64 + lane];
    float2 v1 = x2[(size_t)p1.x * 64 + lane];
    float c0 = __int_as_float(p0.y), c1 = __int_as_float(p1.y);
    a0.x += c0 * v0.x; a0.y += c0 * v0.y;
    a1.x += c1 * v1.x; a1.y += c1 * v1.y;
  }
  if (e < end) {
    int2 p0 = edges[e];
    float2 v0 = x2[(size_t)p0.x * 64 + lane];
    float c0 = __int_as_float(p0.y);
    a0.x += c0 * v0.x; a0.y += c0 * v0.y;
  }
  a0.x += a2.x; a0.y += a2.y;
  a1.x += a3.x; a1.y += a3.y;
  a0.x += a1.x; a0.y += a1.y;
  return a0;
}

// ---------- 4a. layer-1: spmm + bias + selu + fused @W2 (block GEMM) ----------
// 4 rows/block (one per wave). h rows staged in 2KB LDS; then each thread
// computes 1 col x 2 rows of (h @ W). Output = (selu(A_hat xW1 + b1)) @ W2.
__global__ __launch_bounds__(256) void spmm_selu_gemm(
    const int* __restrict__ rowptr, const int2* __restrict__ edges,
    const float* __restrict__ xg, const float* __restrict__ bias,
    const float* __restrict__ W, float* __restrict__ out, int n) {
  __shared__ float hL[4 * 128];
  int wid = threadIdx.x >> 6, lane = threadIdx.x & 63;
  int row = blockIdx.x * 4 + wid;   // grid sized so row < n always
  float2 a = gather_row(rowptr, edges, (const float2*)xg, row, lane);
  float2 b = ((const float2*)bias)[lane];
  float2 h;
  h.x = selu_f(a.x + b.x);
  h.y = selu_f(a.y + b.y);
  ((float2*)hL)[wid * 64 + lane] = h;
  __syncthreads();
  // waves 0,2 -> cols 0..63 ; waves 1,3 -> cols 64..127
  // waves 0,1 -> rows 0,1   ; waves 2,3 -> rows 2,3
  int col = lane + (wid & 1) * 64;
  int rp = threadIdx.x >> 7;
  float acc0 = 0.f, acc1 = 0.f;
#pragma unroll 4
  for (int k = 0; k < 128; ++k) {
    float w = W[k * 128 + col];
    acc0 += hL[(rp * 2) * 128 + k] * w;        // LDS broadcast (wave-uniform)
    acc1 += hL[(rp * 2 + 1) * 128 + k] * w;
  }
  int r0 = blockIdx.x * 4 + rp * 2;
  out[(size_t)r0 * 128 + col]       = acc0;
  out[(size_t)(r0 + 1) * 128 + col] = acc1;
}

// ---------- 4b. layer-2: spmm + bias + selu -> final output ----------
__global__ __launch_bounds__(256) void spmm_ep(
    const int* __restrict__ rowptr, const int2* __restrict__ edges,
    const float* __restrict__ x, const float* __restrict__ bias,
    float* __restrict__ out, int n) {
  int row = blockIdx.x * 4 + (threadIdx.x >> 6);
  if (row >= n) return;
  int lane = threadIdx.x & 63;
  float2 a = gather_row(rowptr, edges, (const float2*)x, row, lane);
  float2 b = ((const float2*)bias)[lane];
  float2 r;
  r.x = selu_f(a.x + b.x);
  r.y = selu_f(a.y + b.y);
  ((float2*)out)[(size_t)row * 64 + lane] = r;
}

extern "C" void kernel_launch(void* const* d_in, const int* in_sizes, int n_in,
                              void* d_out, int out_size, void* d_ws, size_t ws_size,
                              hipStream_t stream) {
  const float* x   = (const float*)d_in[0];
  const int*   src = (const int*)d_in[1];
  const int*   dst = (const int*)d_in[2];
  const float* ew  = (const float*)d_in[3];
  const float* W1  = (const float*)d_in[4];
  const float* b1  = (const float*)d_in[5];
  const float* W2  = (const float*)d_in[6];
  const float* b2  = (const float*)d_in[7];
  float* out = (float*)d_out;

  // workspace layout (byte offsets; 8B for u64/int2, 16B for edges & row bufs)
  char* ws = (char*)d_ws;
  u64*   acc_out  = (u64*)(ws + 0);           //  400,000 B
  u64*   acc_in   = (u64*)(ws + 400000);      //  400,000 B
  float* inv_out  = (float*)(ws + 800000);    //  200,000 B
  float* inv_in   = (float*)(ws + 1000000);   //  200,000 B
  int*   rowptr   = (int*)(ws + 1200000);     //  200,004 B
  int*   nextp    = (int*)(ws + 1400004);     //  200,000 B
  int*   partials = (int*)(ws + 1600004);     //      256 B
  int2*  edges    = (int2*)(ws + 1600272);    // 6,400,000 B (16B aligned)
  float* bufG     = (float*)(ws + 8000272);   // 25,600,000 B
  float* bufB     = bufG + (size_t)N_NODES * FEAT;  // 25,600,000 B

  // zero the two packed degree accumulators
  hipMemsetAsync(d_ws, 0, (size_t)(2 * N_NODES) * sizeof(u64), stream);

  const int NB1K = (N_NODES + 1023) / 1024;    // 49

  // 1. degree atomics || bufG = x @ W1 (graph-independent, overlapped)
  fused_deg_gemm<<<EDGE_BLOCKS + GEMM_BLOCKS, 256, 0, stream>>>(
      src, dst, ew, acc_out, acc_in, x, W1, bufG);
  // 2. norms + CSR rowptr
  node_inv_scan<<<NB1K, 256, 0, stream>>>(acc_out, acc_in, inv_out, inv_in,
                                          partials, N_NODES);
  scan_small<<<1, 64, 0, stream>>>(partials, NB1K);
  scan_write<<<NB1K, 256, 0, stream>>>(acc_in, partials, rowptr, nextp, N_NODES);
  // 3. CSR fill with fused coefficient
  fill_kernel<<<EDGE_BLOCKS, 256, 0, stream>>>(src, dst, ew, inv_out, inv_in,
                                               nextp, edges);

  const int AB = N_NODES / 4;                  // 12500 (4 rows / block, exact)

  // layer 1 + layer-2 GEMM: bufB = selu(A_hat·(x@W1) + b1) @ W2
  spmm_selu_gemm<<<AB, 256, 0, stream>>>(rowptr, edges, bufG, b1, W2, bufB, N_NODES);
  // layer 2: out = selu(A_hat·bufB + b2)
  spmm_ep<<<AB, 256, 0, stream>>>(rowptr, edges, bufB, b2, out, N_NODES);
}

// Round 5
// 333.272 us; speedup vs baseline: 1.4466x; 1.1424x over previous
//
#include <hip/hip_runtime.h>
#include <hip/hip_fp16.h>
#include <math.h>

#define N_NODES 50000
#define N_EDGES 800000
#define FEAT 128
#define EPS_W 1e-12f

// Q24 fixed-point packing: low 40 bits = sum of w*2^24, high 24 bits = count.
#define WSCALE 16777216.0f
#define MASK40 ((1ull << 40) - 1)

#define EDGE_BLOCKS 3125   // 800000 / 256
#define GEMM_BLOCKS 3125   // 50000 / 16

typedef unsigned long long u64;

// ---------- helpers ----------
__device__ __forceinline__ float selu_f(float x) {
  const float scale = 1.0507009873554805f;
  const float alpha = 1.6732632423543772f;
  return x > 0.f ? scale * x : scale * alpha * expm1f(x);
}

// ---------- GEMM body: 16 rows of A (n x 128) @ W (128 x 128) -> fp16 out ------
__device__ __forceinline__ void gemm16_half_body(
    const float* __restrict__ A, const float* __restrict__ W,
    __half* __restrict__ out, int row0, int n, float* aL /*16*128 LDS*/) {
  for (int i = threadIdx.x; i < 16 * 128; i += 256) {
    int r = row0 + (i >> 7);
    aL[i] = (r < n) ? A[row0 * 128 + i] : 0.f;
  }
  __syncthreads();
  int col = threadIdx.x & 63;
  int rg = threadIdx.x >> 6;  // 0..3
  float acc[4][2] = {};
  const float4* a4 = (const float4*)&aL[rg * 4 * 128];
#pragma unroll 8
  for (int k4 = 0; k4 < 32; ++k4) {
    float w0 = W[(4 * k4 + 0) * 128 + col];
    float w1 = W[(4 * k4 + 1) * 128 + col];
    float w2 = W[(4 * k4 + 2) * 128 + col];
    float w3 = W[(4 * k4 + 3) * 128 + col];
    float e0 = W[(4 * k4 + 0) * 128 + col + 64];
    float e1 = W[(4 * k4 + 1) * 128 + col + 64];
    float e2 = W[(4 * k4 + 2) * 128 + col + 64];
    float e3 = W[(4 * k4 + 3) * 128 + col + 64];
#pragma unroll
    for (int r = 0; r < 4; ++r) {
      float4 a = a4[r * 32 + k4];           // ds_read_b128, 2-way (free) pattern
      acc[r][0] += a.x * w0 + a.y * w1 + a.z * w2 + a.w * w3;
      acc[r][1] += a.x * e0 + a.y * e1 + a.z * e2 + a.w * e3;
    }
  }
#pragma unroll
  for (int r = 0; r < 4; ++r) {
    int row = row0 + rg * 4 + r;
    if (row < n) {
      out[(size_t)row * 128 + col]      = __float2half_rn(acc[r][0]);
      out[(size_t)row * 128 + col + 64] = __float2half_rn(acc[r][1]);
    }
  }
}

// ---------- 1. FUSED: degree atomics + rank capture || x@W1 GEMM ----------
// Degree is fabric-atomic-rate bound (~22 atomics/ns) -> GEMM co-schedules free.
// atomicAdd's RETURN gives each edge its rank within its dst row -> fill needs
// no atomics at all.
__global__ __launch_bounds__(256) void fused_deg_gemm(
    const int* __restrict__ src, const int* __restrict__ dst,
    const float* __restrict__ ew,
    u64* __restrict__ acc_out, u64* __restrict__ acc_in,
    unsigned short* __restrict__ rank,
    const float* __restrict__ x, const float* __restrict__ W1,
    __half* __restrict__ bufG) {
  __shared__ float aL[16 * 128];
  if (blockIdx.x & 1) {
    int e = (blockIdx.x >> 1) * 256 + threadIdx.x;
    if (e >= N_EDGES) return;
    int s = src[e], d = dst[e];
    float w = ew[e];
    u64 p = (1ull << 40) | (u64)llrintf(w * WSCALE);
    atomicAdd(&acc_out[s], p);
    u64 old = atomicAdd(&acc_in[d], p);
    rank[e] = (unsigned short)(old >> 40);   // in-edge rank of e within row d
  } else {
    int row0 = (blockIdx.x >> 1) * 16;
    gemm16_half_body(x, W1, bufG, row0, N_NODES, aL);
  }
}

// ---------- 2. per-node inverse norms + scan partials (fused) ----------
__global__ __launch_bounds__(256) void node_inv_scan(
    const u64* __restrict__ acc_out, const u64* __restrict__ acc_in,
    float* __restrict__ inv_out, float* __restrict__ inv_in,
    int* __restrict__ partials, int n) {
  __shared__ int sdata[256];
  int base = blockIdx.x * 1024;
  int sum = 0;
  for (int j = 0; j < 4; ++j) {
    int i = base + j * 256 + threadIdx.x;
    if (i < n) {
      u64 po = acc_out[i], pi = acc_in[i];
      float wo = (float)(po & MASK40) * (1.0f / WSCALE);
      float wi = (float)(pi & MASK40) * (1.0f / WSCALE);
      float co = (float)(po >> 40);
      float ci = (float)(pi >> 40);
      inv_out[i] = (1.0f / sqrtf(fmaxf(wo, EPS_W))) * (1.0f / sqrtf(fmaxf(co, 1.0f)));
      inv_in[i]  = (1.0f / sqrtf(fmaxf(wi, EPS_W))) * (1.0f / sqrtf(fmaxf(ci, 1.0f)));
      sum += (int)(pi >> 40);
    }
  }
  sdata[threadIdx.x] = sum;
  __syncthreads();
  for (int s = 128; s > 0; s >>= 1) {
    if (threadIdx.x < (unsigned)s) sdata[threadIdx.x] += sdata[threadIdx.x + s];
    __syncthreads();
  }
  if (threadIdx.x == 0) partials[blockIdx.x] = sdata[0];
}

__global__ void scan_small(int* __restrict__ partials, int nb) {
  int lane = threadIdx.x;  // launched with 64 threads, nb <= 64
  int v = (lane < nb) ? partials[lane] : 0;
  int incl = v;
#pragma unroll
  for (int off = 1; off < 64; off <<= 1) {
    int tv = __shfl_up(incl, off);
    if (lane >= off) incl += tv;
  }
  if (lane < nb) partials[lane] = incl - v;  // exclusive
}

__global__ __launch_bounds__(256) void scan_write(
    const u64* __restrict__ acc_in, const int* __restrict__ partials,
    int* __restrict__ rowptr, int n) {
  __shared__ int sh[256];
  int t = threadIdx.x;
  int base = blockIdx.x * 1024;
  int c[4], local[4], s = 0;
#pragma unroll
  for (int j = 0; j < 4; ++j) {
    int i = base + t * 4 + j;
    c[j] = (i < n) ? (int)(acc_in[i] >> 40) : 0;
    s += c[j];
    local[j] = s;  // inclusive within thread
  }
  sh[t] = s;
  __syncthreads();
  for (int off = 1; off < 256; off <<= 1) {
    int v = (t >= off) ? sh[t - off] : 0;
    __syncthreads();
    sh[t] += v;
    __syncthreads();
  }
  int thread_excl = sh[t] - s;
  int pbase = partials[blockIdx.x];
#pragma unroll
  for (int j = 0; j < 4; ++j) {
    int i = base + t * 4 + j;
    if (i < n) {
      int excl = pbase + thread_excl + local[j] - c[j];
      rowptr[i] = excl;
      if (i == n - 1) rowptr[n] = excl + c[j];
    }
  }
}

// ---------- 3. ATOMIC-FREE fill: pos = rowptr[dst] + rank ----------
__global__ __launch_bounds__(256) void fill_kernel(
    const int* __restrict__ src, const int* __restrict__ dst,
    const float* __restrict__ ew,
    const float* __restrict__ inv_out, const float* __restrict__ inv_in,
    const int* __restrict__ rowptr, const unsigned short* __restrict__ rank,
    int2* __restrict__ edges) {
  int e = blockIdx.x * 256 + threadIdx.x;
  if (e >= N_EDGES) return;
  int s = src[e], d = dst[e];
  float c = ew[e] * inv_out[s] * inv_in[d];
  int pos = rowptr[d] + (int)rank[e];
  int2 rec; rec.x = s; rec.y = __float_as_int(c);
  edges[pos] = rec;  // single 8B scattered store, no atomic
}

// ---------- gather one dst row from fp16 features: unroll 8 ----------
__device__ __forceinline__ float2 gather_row_h(
    const int* __restrict__ rowptr, const int2* __restrict__ edges,
    const __half2* __restrict__ xh, int row, int lane) {
  int beg = rowptr[row], end = rowptr[row + 1];
  float2 a0 = make_float2(0.f, 0.f), a1 = a0, a2 = a0, a3 = a0;
  int e = beg;
  for (; e + 7 < end; e += 8) {
    int2 p0 = edges[e + 0], p1 = edges[e + 1], p2 = edges[e + 2], p3 = edges[e + 3];
    int2 p4 = edges[e + 4], p5 = edges[e + 5], p6 = edges[e + 6], p7 = edges[e + 7];
    float2 v0 = __half22float2(xh[(size_t)p0.x * 64 + lane]);
    float2 v1 = __half22float2(xh[(size_t)p1.x * 64 + lane]);
    float2 v2 = __half22float2(xh[(size_t)p2.x * 64 + lane]);
    float2 v3 = __half22float2(xh[(size_t)p3.x * 64 + lane]);
    float2 v4 = __half22float2(xh[(size_t)p4.x * 64 + lane]);
    float2 v5 = __half22float2(xh[(size_t)p5.x * 64 + lane]);
    float2 v6 = __half22float2(xh[(size_t)p6.x * 64 + lane]);
    float2 v7 = __half22float2(xh[(size_t)p7.x * 64 + lane]);
    float c0 = __int_as_float(p0.y), c1 = __int_as_float(p1.y);
    float c2 = __int_as_float(p2.y), c3 = __int_as_float(p3.y);
    float c4 = __int_as_float(p4.y), c5 = __int_as_float(p5.y);
    float c6 = __int_as_float(p6.y), c7 = __int_as_float(p7.y);
    a0.x += c0 * v0.x; a0.y += c0 * v0.y;
    a1.x += c1 * v1.x; a1.y += c1 * v1.y;
    a2.x += c2 * v2.x; a2.y += c2 * v2.y;
    a3.x += c3 * v3.x; a3.y += c3 * v3.y;
    a0.x += c4 * v4.x; a0.y += c4 * v4.y;
    a1.x += c5 * v5.x; a1.y += c5 * v5.y;
    a2.x += c6 * v6.x; a2.y += c6 * v6.y;
    a3.x += c7 * v7.x; a3.y += c7 * v7.y;
  }
  for (; e + 1 < end; e += 2) {
    int2 p0 = edges[e], p1 = edges[e + 1];
    float2 v0 = __half22float2(xh[(size_t)p0.x * 64 + lane]);
    float2 v1 = __half22float2(xh[(size_t)p1.x * 64 + lane]);
    float c0 = __int_as_float(p0.y), c1 = __int_as_float(p1.y);
    a0.x += c0 * v0.x; a0.y += c0 * v0.y;
    a1.x += c1 * v1.x; a1.y += c1 * v1.y;
  }
  if (e < end) {
    int2 p0 = edges[e];
    float2 v0 = __half22float2(xh[(size_t)p0.x * 64 + lane]);
    float c0 = __int_as_float(p0.y);
    a0.x += c0 * v0.x; a0.y += c0 * v0.y;
  }
  a0.x += a2.x; a0.y += a2.y;
  a1.x += a3.x; a1.y += a3.y;
  a0.x += a1.x; a0.y += a1.y;
  return a0;
}

// ---------- 4a. layer-1: spmm(fp16 g) + bias + selu + fused @W2 -> fp16 bufB ---
__global__ __launch_bounds__(256) void spmm_selu_gemm(
    const int* __restrict__ rowptr, const int2* __restrict__ edges,
    const __half2* __restrict__ g, const float* __restrict__ bias,
    const float* __restrict__ W, __half* __restrict__ out, int n) {
  __shared__ float hL[4 * 128];
  int wid = threadIdx.x >> 6, lane = threadIdx.x & 63;
  int row = blockIdx.x * 4 + wid;   // grid exact: row < n always
  float2 a = gather_row_h(rowptr, edges, g, row, lane);
  float2 b = ((const float2*)bias)[lane];
  float2 h;
  h.x = selu_f(a.x + b.x);
  h.y = selu_f(a.y + b.y);
  ((float2*)hL)[wid * 64 + lane] = h;
  __syncthreads();
  // waves 0,2 -> cols 0..63 ; waves 1,3 -> cols 64..127
  // threads <128 -> rows 0,1 ; threads >=128 -> rows 2,3
  int col = lane + (wid & 1) * 64;
  int rp = threadIdx.x >> 7;
  const float4* h0 = (const float4*)&hL[(rp * 2) * 128];
  const float4* h1 = (const float4*)&hL[(rp * 2 + 1) * 128];
  float acc0 = 0.f, acc1 = 0.f;
#pragma unroll 8
  for (int k4 = 0; k4 < 32; ++k4) {
    float4 ha = h0[k4];                       // ds_read_b128, wave-uniform bcast
    float4 hb = h1[k4];
    float w0 = W[(4 * k4 + 0) * 128 + col];
    float w1 = W[(4 * k4 + 1) * 128 + col];
    float w2 = W[(4 * k4 + 2) * 128 + col];
    float w3 = W[(4 * k4 + 3) * 128 + col];
    acc0 += ha.x * w0 + ha.y * w1 + ha.z * w2 + ha.w * w3;
    acc1 += hb.x * w0 + hb.y * w1 + hb.z * w2 + hb.w * w3;
  }
  int r0 = blockIdx.x * 4 + rp * 2;
  out[(size_t)r0 * 128 + col]       = __float2half_rn(acc0);
  out[(size_t)(r0 + 1) * 128 + col] = __float2half_rn(acc1);
}

// ---------- 4b. layer-2: spmm(fp16 bufB) + bias + selu -> fp32 output ----------
__global__ __launch_bounds__(256) void spmm_ep(
    const int* __restrict__ rowptr, const int2* __restrict__ edges,
    const __half2* __restrict__ xh, const float* __restrict__ bias,
    float* __restrict__ out, int n) {
  int row = blockIdx.x * 4 + (threadIdx.x >> 6);   // grid exact
  int lane = threadIdx.x & 63;
  float2 a = gather_row_h(rowptr, edges, xh, row, lane);
  float2 b = ((const float2*)bias)[lane];
  float2 r;
  r.x = selu_f(a.x + b.x);
  r.y = selu_f(a.y + b.y);
  ((float2*)out)[(size_t)row * 64 + lane] = r;
}

extern "C" void kernel_launch(void* const* d_in, const int* in_sizes, int n_in,
                              void* d_out, int out_size, void* d_ws, size_t ws_size,
                              hipStream_t stream) {
  const float* x   = (const float*)d_in[0];
  const int*   src = (const int*)d_in[1];
  const int*   dst = (const int*)d_in[2];
  const float* ew  = (const float*)d_in[3];
  const float* W1  = (const float*)d_in[4];
  const float* b1  = (const float*)d_in[5];
  const float* W2  = (const float*)d_in[6];
  const float* b2  = (const float*)d_in[7];
  float* out = (float*)d_out;

  // workspace layout (byte offsets; 8B for u64/int2, 16B for edges & fp16 bufs)
  char* ws = (char*)d_ws;
  u64*   acc_out  = (u64*)(ws + 0);             //   400,000 B
  u64*   acc_in   = (u64*)(ws + 400000);        //   400,000 B
  float* inv_out  = (float*)(ws + 800000);      //   200,000 B
  float* inv_in   = (float*)(ws + 1000000);     //   200,000 B
  int*   rowptr   = (int*)(ws + 1200000);       //   200,004 B
  int*   partials = (int*)(ws + 1400004);       //       256 B
  unsigned short* rank = (unsigned short*)(ws + 1400260);  // 1,600,000 B
  int2*  edges    = (int2*)(ws + 3000272);      // 6,400,000 B (16B aligned)
  __half* bufG    = (__half*)(ws + 9400272);    // 12,800,000 B (fp16)
  __half* bufB    = (__half*)(ws + 22200272);   // 12,800,000 B (fp16)

  // zero the two packed degree accumulators
  hipMemsetAsync(d_ws, 0, (size_t)(2 * N_NODES) * sizeof(u64), stream);

  const int NB1K = (N_NODES + 1023) / 1024;    // 49

  // 1. degree atomics + rank capture || bufG = fp16(x @ W1)  (overlapped)
  fused_deg_gemm<<<EDGE_BLOCKS + GEMM_BLOCKS, 256, 0, stream>>>(
      src, dst, ew, acc_out, acc_in, rank, x, W1, bufG);
  // 2. norms + CSR rowptr
  node_inv_scan<<<NB1K, 256, 0, stream>>>(acc_out, acc_in, inv_out, inv_in,
                                          partials, N_NODES);
  scan_small<<<1, 64, 0, stream>>>(partials, NB1K);
  scan_write<<<NB1K, 256, 0, stream>>>(acc_in, partials, rowptr, N_NODES);
  // 3. atomic-free CSR fill
  fill_kernel<<<EDGE_BLOCKS, 256, 0, stream>>>(src, dst, ew, inv_out, inv_in,
                                               rowptr, rank, edges);

  const int AB = N_NODES / 4;                  // 12500 (4 rows / block, exact)

  // layer 1 + layer-2 GEMM: bufB = fp16( selu(A_hat·(x@W1) + b1) @ W2 )
  spmm_selu_gemm<<<AB, 256, 0, stream>>>(rowptr, edges, (const __half2*)bufG,
                                         b1, W2, bufB, N_NODES);
  // layer 2: out = selu(A_hat·bufB + b2)
  spmm_ep<<<AB, 256, 0, stream>>>(rowptr, edges, (const __half2*)bufB, b2,
                                  out, N_NODES);
}

// Round 6
// 308.866 us; speedup vs baseline: 1.5609x; 1.0790x over previous
//
#include <hip/hip_runtime.h>
#include <hip/hip_fp16.h>
#include <math.h>

#define N_NODES 50000
#define N_EDGES 800000
#define FEAT 128
#define EPS_W 1e-12f

// Q24 fixed-point packing: low 40 bits = sum of w*2^24, high 24 bits = count.
#define WSCALE 16777216.0f
#define MASK40 ((1ull << 40) - 1)

#define EDGE_BLOCKS 3125   // 800000 / 256
#define GEMM_BLOCKS 3125   // 50000 / 16

typedef unsigned long long u64;

// ---------- helpers ----------
__device__ __forceinline__ float selu_f(float x) {
  const float scale = 1.0507009873554805f;
  const float alpha = 1.6732632423543772f;
  return x > 0.f ? scale * x : scale * alpha * expm1f(x);
}

__device__ __forceinline__ float2 h2f2(unsigned int u) {
  __half2 h = *reinterpret_cast<__half2*>(&u);
  return __half22float2(h);
}

// ---------- GEMM body: 16 rows of A (n x 128) @ W (128 x 128) -> fp16 out ------
__device__ __forceinline__ void gemm16_half_body(
    const float* __restrict__ A, const float* __restrict__ W,
    __half* __restrict__ out, int row0, int n, float* aL /*16*128 LDS*/) {
  for (int i = threadIdx.x; i < 16 * 128; i += 256) {
    int r = row0 + (i >> 7);
    aL[i] = (r < n) ? A[row0 * 128 + i] : 0.f;
  }
  __syncthreads();
  int col = threadIdx.x & 63;
  int rg = threadIdx.x >> 6;  // 0..3
  float acc[4][2] = {};
  const float4* a4 = (const float4*)&aL[rg * 4 * 128];
#pragma unroll 8
  for (int k4 = 0; k4 < 32; ++k4) {
    float w0 = W[(4 * k4 + 0) * 128 + col];
    float w1 = W[(4 * k4 + 1) * 128 + col];
    float w2 = W[(4 * k4 + 2) * 128 + col];
    float w3 = W[(4 * k4 + 3) * 128 + col];
    float e0 = W[(4 * k4 + 0) * 128 + col + 64];
    float e1 = W[(4 * k4 + 1) * 128 + col + 64];
    float e2 = W[(4 * k4 + 2) * 128 + col + 64];
    float e3 = W[(4 * k4 + 3) * 128 + col + 64];
#pragma unroll
    for (int r = 0; r < 4; ++r) {
      float4 a = a4[r * 32 + k4];
      acc[r][0] += a.x * w0 + a.y * w1 + a.z * w2 + a.w * w3;
      acc[r][1] += a.x * e0 + a.y * e1 + a.z * e2 + a.w * e3;
    }
  }
#pragma unroll
  for (int r = 0; r < 4; ++r) {
    int row = row0 + rg * 4 + r;
    if (row < n) {
      out[(size_t)row * 128 + col]      = __float2half_rn(acc[r][0]);
      out[(size_t)row * 128 + col + 64] = __float2half_rn(acc[r][1]);
    }
  }
}

// ---------- 1. FUSED: degree atomics + rank capture || x@W1 GEMM ----------
__global__ __launch_bounds__(256) void fused_deg_gemm(
    const int* __restrict__ src, const int* __restrict__ dst,
    const float* __restrict__ ew,
    u64* __restrict__ acc_out, u64* __restrict__ acc_in,
    unsigned short* __restrict__ rank,
    const float* __restrict__ x, const float* __restrict__ W1,
    __half* __restrict__ bufG) {
  __shared__ float aL[16 * 128];
  if (blockIdx.x & 1) {
    int e = (blockIdx.x >> 1) * 256 + threadIdx.x;
    if (e >= N_EDGES) return;
    int s = src[e], d = dst[e];
    float w = ew[e];
    u64 p = (1ull << 40) | (u64)llrintf(w * WSCALE);
    atomicAdd(&acc_out[s], p);
    u64 old = atomicAdd(&acc_in[d], p);
    rank[e] = (unsigned short)(old >> 40);   // in-edge rank of e within row d
  } else {
    int row0 = (blockIdx.x >> 1) * 16;
    gemm16_half_body(x, W1, bufG, row0, N_NODES, aL);
  }
}

// ---------- 2. per-node inverse norms + scan partials (fused) ----------
__global__ __launch_bounds__(256) void node_inv_scan(
    const u64* __restrict__ acc_out, const u64* __restrict__ acc_in,
    float* __restrict__ inv_out, float* __restrict__ inv_in,
    int* __restrict__ partials, int n) {
  __shared__ int sdata[256];
  int base = blockIdx.x * 1024;
  int sum = 0;
  for (int j = 0; j < 4; ++j) {
    int i = base + j * 256 + threadIdx.x;
    if (i < n) {
      u64 po = acc_out[i], pi = acc_in[i];
      float wo = (float)(po & MASK40) * (1.0f / WSCALE);
      float wi = (float)(pi & MASK40) * (1.0f / WSCALE);
      float co = (float)(po >> 40);
      float ci = (float)(pi >> 40);
      inv_out[i] = (1.0f / sqrtf(fmaxf(wo, EPS_W))) * (1.0f / sqrtf(fmaxf(co, 1.0f)));
      inv_in[i]  = (1.0f / sqrtf(fmaxf(wi, EPS_W))) * (1.0f / sqrtf(fmaxf(ci, 1.0f)));
      sum += (int)(pi >> 40);
    }
  }
  sdata[threadIdx.x] = sum;
  __syncthreads();
  for (int s = 128; s > 0; s >>= 1) {
    if (threadIdx.x < (unsigned)s) sdata[threadIdx.x] += sdata[threadIdx.x + s];
    __syncthreads();
  }
  if (threadIdx.x == 0) partials[blockIdx.x] = sdata[0];
}

__global__ void scan_small(int* __restrict__ partials, int nb) {
  int lane = threadIdx.x;  // launched with 64 threads, nb <= 64
  int v = (lane < nb) ? partials[lane] : 0;
  int incl = v;
#pragma unroll
  for (int off = 1; off < 64; off <<= 1) {
    int tv = __shfl_up(incl, off);
    if (lane >= off) incl += tv;
  }
  if (lane < nb) partials[lane] = incl - v;  // exclusive
}

__global__ __launch_bounds__(256) void scan_write(
    const u64* __restrict__ acc_in, const int* __restrict__ partials,
    int* __restrict__ rowptr, int n) {
  __shared__ int sh[256];
  int t = threadIdx.x;
  int base = blockIdx.x * 1024;
  int c[4], local[4], s = 0;
#pragma unroll
  for (int j = 0; j < 4; ++j) {
    int i = base + t * 4 + j;
    c[j] = (i < n) ? (int)(acc_in[i] >> 40) : 0;
    s += c[j];
    local[j] = s;  // inclusive within thread
  }
  sh[t] = s;
  __syncthreads();
  for (int off = 1; off < 256; off <<= 1) {
    int v = (t >= off) ? sh[t - off] : 0;
    __syncthreads();
    sh[t] += v;
    __syncthreads();
  }
  int thread_excl = sh[t] - s;
  int pbase = partials[blockIdx.x];
#pragma unroll
  for (int j = 0; j < 4; ++j) {
    int i = base + t * 4 + j;
    if (i < n) {
      int excl = pbase + thread_excl + local[j] - c[j];
      rowptr[i] = excl;
      if (i == n - 1) rowptr[n] = excl + c[j];
    }
  }
}

// ---------- 3. ATOMIC-FREE fill: pos = rowptr[dst] + rank ----------
__global__ __launch_bounds__(256) void fill_kernel(
    const int* __restrict__ src, const int* __restrict__ dst,
    const float* __restrict__ ew,
    const float* __restrict__ inv_out, const float* __restrict__ inv_in,
    const int* __restrict__ rowptr, const unsigned short* __restrict__ rank,
    int2* __restrict__ edges) {
  int e = blockIdx.x * 256 + threadIdx.x;
  if (e >= N_EDGES) return;
  int s = src[e], d = dst[e];
  float c = ew[e] * inv_out[s] * inv_in[d];
  int pos = rowptr[d] + (int)rank[e];
  int2 rec; rec.x = s; rec.y = __float_as_int(c);
  edges[pos] = rec;  // single 8B scattered store, no atomic
}

// ---------- half-wave gather: 32 lanes cover a 128-wide fp16 row ----------
// Each lane owns 4 cols (uint2 = half4 load), float4 fp32 accumulator.
// Per-edge wave cost is HALVED vs full-wave (two rows gathered per wave).
__device__ __forceinline__ float4 gather_row_half(
    const int* __restrict__ rowptr, const int2* __restrict__ edges,
    const uint2* __restrict__ xh /* row stride 32 */, int row, int sub) {
  int beg = rowptr[row], end = rowptr[row + 1];
  float4 acc = make_float4(0.f, 0.f, 0.f, 0.f);
  int e = beg;
  for (; e + 7 < end; e += 8) {
    int2 p0 = edges[e + 0], p1 = edges[e + 1], p2 = edges[e + 2], p3 = edges[e + 3];
    int2 p4 = edges[e + 4], p5 = edges[e + 5], p6 = edges[e + 6], p7 = edges[e + 7];
    uint2 q0 = xh[(size_t)p0.x * 32 + sub];
    uint2 q1 = xh[(size_t)p1.x * 32 + sub];
    uint2 q2 = xh[(size_t)p2.x * 32 + sub];
    uint2 q3 = xh[(size_t)p3.x * 32 + sub];
    uint2 q4 = xh[(size_t)p4.x * 32 + sub];
    uint2 q5 = xh[(size_t)p5.x * 32 + sub];
    uint2 q6 = xh[(size_t)p6.x * 32 + sub];
    uint2 q7 = xh[(size_t)p7.x * 32 + sub];
#define ACC_EDGE(P, Q)                                              \
    {                                                               \
      float cc = __int_as_float(P.y);                               \
      float2 lo = h2f2(Q.x);                                        \
      float2 hi = h2f2(Q.y);                                        \
      acc.x += cc * lo.x; acc.y += cc * lo.y;                       \
      acc.z += cc * hi.x; acc.w += cc * hi.y;                       \
    }
    ACC_EDGE(p0, q0) ACC_EDGE(p1, q1) ACC_EDGE(p2, q2) ACC_EDGE(p3, q3)
    ACC_EDGE(p4, q4) ACC_EDGE(p5, q5) ACC_EDGE(p6, q6) ACC_EDGE(p7, q7)
  }
  for (; e < end; ++e) {
    int2 p0 = edges[e];
    uint2 q0 = xh[(size_t)p0.x * 32 + sub];
    ACC_EDGE(p0, q0)
  }
#undef ACC_EDGE
  return acc;
}

// ---------- 4a. layer-1: spmm(fp16 g) + bias + selu + fused @W2 -> fp16 bufB ---
// 8 rows/block: 4 waves x 2 half-wave rows. GEMM: 4 outputs/thread, 2x W reuse.
__global__ __launch_bounds__(256) void spmm_selu_gemm(
    const int* __restrict__ rowptr, const int2* __restrict__ edges,
    const uint2* __restrict__ g, const float* __restrict__ bias,
    const float* __restrict__ W, __half* __restrict__ out, int n) {
  __shared__ float hL[8 * 128];
  int wid = threadIdx.x >> 6, lane = threadIdx.x & 63;
  int half = lane >> 5, sub = lane & 31;
  int lrow = wid * 2 + half;                 // 0..7 within block
  int row = blockIdx.x * 8 + lrow;           // grid exact: row < n
  float4 a = gather_row_half(rowptr, edges, g, row, sub);
  float4 b = ((const float4*)bias)[sub];
  float4 h;
  h.x = selu_f(a.x + b.x);
  h.y = selu_f(a.y + b.y);
  h.z = selu_f(a.z + b.z);
  h.w = selu_f(a.w + b.w);
  ((float4*)hL)[lrow * 32 + sub] = h;
  __syncthreads();
  // GEMM: col = t&127; rq = t>>7 covers rows rq*4..rq*4+3
  int col = threadIdx.x & 127;
  int rq = threadIdx.x >> 7;
  const float4* h4 = (const float4*)&hL[rq * 4 * 128];
  float acc0 = 0.f, acc1 = 0.f, acc2 = 0.f, acc3 = 0.f;
#pragma unroll 8
  for (int k4 = 0; k4 < 32; ++k4) {
    float w0 = W[(4 * k4 + 0) * 128 + col];
    float w1 = W[(4 * k4 + 1) * 128 + col];
    float w2 = W[(4 * k4 + 2) * 128 + col];
    float w3 = W[(4 * k4 + 3) * 128 + col];
    float4 h0 = h4[0 * 32 + k4];             // broadcast ds_read_b128 (free)
    float4 h1 = h4[1 * 32 + k4];
    float4 h2 = h4[2 * 32 + k4];
    float4 h3 = h4[3 * 32 + k4];
    acc0 += h0.x * w0 + h0.y * w1 + h0.z * w2 + h0.w * w3;
    acc1 += h1.x * w0 + h1.y * w1 + h1.z * w2 + h1.w * w3;
    acc2 += h2.x * w0 + h2.y * w1 + h2.z * w2 + h2.w * w3;
    acc3 += h3.x * w0 + h3.y * w1 + h3.z * w2 + h3.w * w3;
  }
  size_t r0 = (size_t)(blockIdx.x * 8 + rq * 4);
  out[(r0 + 0) * 128 + col] = __float2half_rn(acc0);
  out[(r0 + 1) * 128 + col] = __float2half_rn(acc1);
  out[(r0 + 2) * 128 + col] = __float2half_rn(acc2);
  out[(r0 + 3) * 128 + col] = __float2half_rn(acc3);
}

// ---------- 4b. layer-2: spmm(fp16 bufB) + bias + selu -> fp32 output ----------
__global__ __launch_bounds__(256) void spmm_ep(
    const int* __restrict__ rowptr, const int2* __restrict__ edges,
    const uint2* __restrict__ xh, const float* __restrict__ bias,
    float* __restrict__ out, int n) {
  int wid = threadIdx.x >> 6, lane = threadIdx.x & 63;
  int half = lane >> 5, sub = lane & 31;
  int row = blockIdx.x * 8 + wid * 2 + half;   // grid exact
  float4 a = gather_row_half(rowptr, edges, xh, row, sub);
  float4 b = ((const float4*)bias)[sub];
  float4 r;
  r.x = selu_f(a.x + b.x);
  r.y = selu_f(a.y + b.y);
  r.z = selu_f(a.z + b.z);
  r.w = selu_f(a.w + b.w);
  ((float4*)out)[(size_t)row * 32 + sub] = r;
}

extern "C" void kernel_launch(void* const* d_in, const int* in_sizes, int n_in,
                              void* d_out, int out_size, void* d_ws, size_t ws_size,
                              hipStream_t stream) {
  const float* x   = (const float*)d_in[0];
  const int*   src = (const int*)d_in[1];
  const int*   dst = (const int*)d_in[2];
  const float* ew  = (const float*)d_in[3];
  const float* W1  = (const float*)d_in[4];
  const float* b1  = (const float*)d_in[5];
  const float* W2  = (const float*)d_in[6];
  const float* b2  = (const float*)d_in[7];
  float* out = (float*)d_out;

  // workspace layout (byte offsets; 8B for u64/int2, 16B for edges & fp16 bufs)
  char* ws = (char*)d_ws;
  u64*   acc_out  = (u64*)(ws + 0);             //   400,000 B
  u64*   acc_in   = (u64*)(ws + 400000);        //   400,000 B
  float* inv_out  = (float*)(ws + 800000);      //   200,000 B
  float* inv_in   = (float*)(ws + 1000000);     //   200,000 B
  int*   rowptr   = (int*)(ws + 1200000);       //   200,004 B
  int*   partials = (int*)(ws + 1400004);       //       256 B
  unsigned short* rank = (unsigned short*)(ws + 1400260);  // 1,600,000 B
  int2*  edges    = (int2*)(ws + 3000272);      // 6,400,000 B (16B aligned)
  __half* bufG    = (__half*)(ws + 9400272);    // 12,800,000 B (fp16)
  __half* bufB    = (__half*)(ws + 22200272);   // 12,800,000 B (fp16)

  // zero the two packed degree accumulators
  hipMemsetAsync(d_ws, 0, (size_t)(2 * N_NODES) * sizeof(u64), stream);

  const int NB1K = (N_NODES + 1023) / 1024;    // 49

  // 1. degree atomics + rank capture || bufG = fp16(x @ W1)  (overlapped)
  fused_deg_gemm<<<EDGE_BLOCKS + GEMM_BLOCKS, 256, 0, stream>>>(
      src, dst, ew, acc_out, acc_in, rank, x, W1, bufG);
  // 2. norms + CSR rowptr
  node_inv_scan<<<NB1K, 256, 0, stream>>>(acc_out, acc_in, inv_out, inv_in,
                                          partials, N_NODES);
  scan_small<<<1, 64, 0, stream>>>(partials, NB1K);
  scan_write<<<NB1K, 256, 0, stream>>>(acc_in, partials, rowptr, N_NODES);
  // 3. atomic-free CSR fill
  fill_kernel<<<EDGE_BLOCKS, 256, 0, stream>>>(src, dst, ew, inv_out, inv_in,
                                               rowptr, rank, edges);

  const int RB8 = N_NODES / 8;                 // 6250 (8 rows / block, exact)

  // layer 1 + layer-2 GEMM: bufB = fp16( selu(A_hat·(x@W1) + b1) @ W2 )
  spmm_selu_gemm<<<RB8, 256, 0, stream>>>(rowptr, edges, (const uint2*)bufG,
                                          b1, W2, bufB, N_NODES);
  // layer 2: out = selu(A_hat·bufB + b2)
  spmm_ep<<<RB8, 256, 0, stream>>>(rowptr, edges, (const uint2*)bufB, b2,
                                   out, N_NODES);
}